// Round 7
// baseline (522.997 us; speedup 1.0000x reference)
//
#include <hip/hip_runtime.h>
#include <stdint.h>

typedef unsigned short u16;
typedef __attribute__((ext_vector_type(8))) short bf16x8;   // 8 bf16 (4 VGPRs) — MFMA A/B frag
typedef __attribute__((ext_vector_type(4))) float f32x4;    // MFMA C/D frag

static __device__ __forceinline__ u16 f2bf(float f) {
  uint32_t u = __float_as_uint(f);
  return (u16)((u + 0x7fffu + ((u >> 16) & 1u)) >> 16);   // RNE
}
static __device__ __forceinline__ float bf2f(u16 h) {
  return __uint_as_float(((uint32_t)h) << 16);
}

static __device__ __forceinline__ void gload_lds16(const void* g, void* l) {
  __builtin_amdgcn_global_load_lds((const __attribute__((address_space(1))) void*)g,
                                   (__attribute__((address_space(3))) void*)l, 16, 0, 0);
}

// ---------------- elementwise f32 -> bf16 cast ----------------
__global__ __launch_bounds__(256) void cast_bf16_kernel(const float* __restrict__ in,
                                                        u16* __restrict__ out, int n4) {
  int idx = blockIdx.x * 256 + threadIdx.x;
  if (idx >= n4) return;
  float4 v = ((const float4*)in)[idx];
  u16 o0 = f2bf(v.x), o1 = f2bf(v.y), o2 = f2bf(v.z), o3 = f2bf(v.w);
  uint2 packed;
  packed.x = (uint32_t)o0 | ((uint32_t)o1 << 16);
  packed.y = (uint32_t)o2 | ((uint32_t)o3 << 16);
  ((uint2*)out)[idx] = packed;
}

// -------- deg prep: f32 [4096][4096] -> bf16 row-major AND bf16 transposed --------
__global__ __launch_bounds__(256) void deg_prep_kernel(const float* __restrict__ in,
                                                       u16* __restrict__ degb,
                                                       u16* __restrict__ degt) {
  __shared__ float t[64][72];
  const int r0 = blockIdx.y * 64, c0 = blockIdx.x * 64;
  const int tid = threadIdx.x;
  const int rr = tid >> 4;          // 0..15
  const int c4 = (tid & 15) * 4;
#pragma unroll
  for (int s = 0; s < 4; ++s) {
    const int row = r0 + rr + s * 16;
    float4 v = *(const float4*)&in[(size_t)row * 4096 + c0 + c4];
    *(float4*)&t[rr + s * 16][c4] = v;
    uint2 p;
    p.x = (uint32_t)f2bf(v.x) | ((uint32_t)f2bf(v.y) << 16);
    p.y = (uint32_t)f2bf(v.z) | ((uint32_t)f2bf(v.w) << 16);
    *(uint2*)&degb[(size_t)row * 4096 + c0 + c4] = p;
  }
  __syncthreads();
  const int oc = tid >> 2;          // 0..63  (output row = input col)
  const int or16 = (tid & 3) * 16;
  bf16x8 o0, o1;
#pragma unroll
  for (int u = 0; u < 8; ++u) o0[u] = (short)f2bf(t[or16 + u][oc]);
#pragma unroll
  for (int u = 0; u < 8; ++u) o1[u] = (short)f2bf(t[or16 + 8 + u][oc]);
  *(bf16x8*)&degt[(size_t)(c0 + oc) * 4096 + r0 + or16] = o0;
  *(bf16x8*)&degt[(size_t)(c0 + oc) * 4096 + r0 + or16 + 8] = o1;
}

// ---------------- transpose: bf16 [4096][4096] -> bf16 transposed ----------------
__global__ __launch_bounds__(256) void transpose_bf16_kernel(const u16* __restrict__ in,
                                                             u16* __restrict__ out) {
  __shared__ u16 t[64][72];
  const int r0 = blockIdx.y * 64, c0 = blockIdx.x * 64;
  const int tid = threadIdx.x;
  const int rr = tid >> 3;
  const int c8 = (tid & 7) * 8;
#pragma unroll
  for (int s = 0; s < 2; ++s) {
    bf16x8 v = *(const bf16x8*)&in[(size_t)(r0 + rr + s * 32) * 4096 + c0 + c8];
    *(bf16x8*)&t[rr + s * 32][c8] = v;
  }
  __syncthreads();
  const int oc = tid >> 2;
  const int or16 = (tid & 3) * 16;
  bf16x8 o0, o1;
#pragma unroll
  for (int u = 0; u < 8; ++u) o0[u] = (short)t[or16 + u][oc];
#pragma unroll
  for (int u = 0; u < 8; ++u) o1[u] = (short)t[or16 + 8 + u][oc];
  *(bf16x8*)&out[(size_t)(c0 + oc) * 4096 + r0 + or16] = o0;
  *(bf16x8*)&out[(size_t)(c0 + oc) * 4096 + r0 + or16 + 8] = o1;
}

// ---------------- combine 4 split-K partials + leaky -> bf16 ----------------
__global__ __launch_bounds__(256) void combine_leaky_kernel(const float* __restrict__ P,
                                                            u16* __restrict__ out, int n4) {
  int idx = blockIdx.x * 256 + threadIdx.x;
  if (idx >= n4) return;
  const size_t SL = (size_t)4096 * 512;
  float4 a = ((const float4*)P)[idx];
  float4 b = ((const float4*)(P + SL))[idx];
  float4 c = ((const float4*)(P + 2 * SL))[idx];
  float4 d = ((const float4*)(P + 3 * SL))[idx];
  float s0 = (a.x + b.x) + (c.x + d.x);
  float s1 = (a.y + b.y) + (c.y + d.y);
  float s2 = (a.z + b.z) + (c.z + d.z);
  float s3 = (a.w + b.w) + (c.w + d.w);
  s0 = s0 >= 0.f ? s0 : 0.1f * s0;
  s1 = s1 >= 0.f ? s1 : 0.1f * s1;
  s2 = s2 >= 0.f ? s2 : 0.1f * s2;
  s3 = s3 >= 0.f ? s3 : 0.1f * s3;
  uint2 p;
  p.x = (uint32_t)f2bf(s0) | ((uint32_t)f2bf(s1) << 16);
  p.y = (uint32_t)f2bf(s2) | ((uint32_t)f2bf(s3) << 16);
  ((uint2*)out)[idx] = p;
}

// ------------- kern[i][t] = sum over 64 kpart slices (deterministic) -------------
__global__ __launch_bounds__(256) void kpart_reduce_kernel(const float* __restrict__ kp,
                                                           float* __restrict__ kern) {
  int idx = blockIdx.x * 256 + threadIdx.x;   // 0..36863 (= 4096*9)
  if (idx >= 4096 * 9) return;
  float s = 0.f;
#pragma unroll
  for (int sl = 0; sl < 64; ++sl) s += kp[(size_t)sl * 36864 + idx];
  kern[idx] = s;
}

// ---------------- depthwise 3x3 conv + leaky -> bf16 ----------------
__global__ __launch_bounds__(256) void dwconv_kernel(const float* __restrict__ x,
                                                     const float* __restrict__ kern,
                                                     u16* __restrict__ V) {
  const int ch = blockIdx.x;
  __shared__ float img[4096];
  const float* src = x + (size_t)ch * 4096;
#pragma unroll
  for (int s = 0; s < 4; ++s)
    ((float4*)img)[s * 256 + threadIdx.x] = ((const float4*)src)[s * 256 + threadIdx.x];
  float kv[9];
#pragma unroll
  for (int t = 0; t < 9; ++t) kv[t] = kern[(size_t)ch * 9 + t];
  __syncthreads();
#pragma unroll
  for (int s = 0; s < 16; ++s) {
    const int p = s * 256 + threadIdx.x;
    const int h = p >> 6, w = p & 63;
    float sum = 0.f;
#pragma unroll
    for (int dh = -1; dh <= 1; ++dh) {
      const int hh = h + dh;
      if ((unsigned)hh < 64u) {
#pragma unroll
        for (int dw = -1; dw <= 1; ++dw) {
          const int wwi = w + dw;
          if ((unsigned)wwi < 64u) sum += img[hh * 64 + wwi] * kv[(dh + 1) * 3 + (dw + 1)];
        }
      }
    }
    sum = sum >= 0.f ? sum : 0.1f * sum;
    V[(size_t)ch * 4096 + p] = f2bf(sum);
  }
}

// ---------------- NT GEMM: C[m][n] = sum_k A[m][k]*B[n][k], bf16 in, fp32 acc ----------------
// EPI: 1 = sigmoid -> bf16 ; 3 = raw f32 partial (split-K over blockIdx.z) ;
//      4 = fused H+kern: no C write; kpart[slice][i][t] += leaky(H)*W2 (Cout=kpart, bias=W2) ;
//      5 = +bias + bf16(deg)*att -> f32 out
// Grid: dim3(gx, gy, kslices); XCD-aware bijective block swizzle (gx*gy % 8 == 0).
// LDS XOR swizzle (rule 21, both-sides): dest linear, source col pre-swizzled seg^(row&7),
// fragment reads apply the same XOR. Residual 2-way aliasing = free (m136).
template <int EPI>
__global__ __launch_bounds__(256, 4) void gemm_nt(const u16* __restrict__ A,
                                                  const u16* __restrict__ B,
                                                  void* __restrict__ Cout,
                                                  int M, int N, int K,
                                                  const float* __restrict__ bias,
                                                  const u16* __restrict__ att,
                                                  const u16* __restrict__ degb) {
  __shared__ u16 Asm[128 * 64];
  __shared__ u16 Bsm[128 * 64];
  const int tid = threadIdx.x;
  const int lane = tid & 63;
  const int wid = tid >> 6;
  const int wr = wid >> 1, wc = wid & 1;       // 2x2 wave grid, 64x64 per wave
  // XCD swizzle: consecutive blocks land on the same XCD -> shared operand panels L2-hit
  const int nwg = gridDim.x * gridDim.y;
  int lin = blockIdx.y * gridDim.x + blockIdx.x;
  lin = (lin & 7) * (nwg >> 3) + (lin >> 3);   // bijective (nwg % 8 == 0)
  const int bn = (lin % gridDim.x) * 128;
  const int bm = (lin / gridDim.x) * 128;
  // split-K slice
  const int kper = K / gridDim.z;
  const int k0 = blockIdx.z * kper, k1 = k0 + kper;

  const int srow = tid >> 3;                    // 0..31 staging row
  const int sseg = tid & 7;                     // 16B segment idx within 64-elem row
  const int ssw  = (sseg ^ (srow & 7)) * 8;     // swizzled SOURCE elem offset
  const int l15 = lane & 15;
  const int seg0 = lane >> 4;                   // 0..3 base segment of this lane quad
  const int lx7 = l15 & 7;                      // read-side XOR key (row&7)

  f32x4 acc[4][4];
#pragma unroll
  for (int m = 0; m < 4; ++m)
#pragma unroll
    for (int n = 0; n < 4; ++n) acc[m][n] = (f32x4){0.f, 0.f, 0.f, 0.f};

  const size_t aBase = (size_t)bm * K;
  const size_t bBase = (size_t)bn * K;

  for (int kt = k0; kt < k1; kt += 64) {
    __syncthreads();
#pragma unroll
    for (int bi = 0; bi < 4; ++bi) {
      const u16* ga = A + aBase + (size_t)(bi * 32 + srow) * K + kt + ssw;
      gload_lds16(ga, &Asm[(bi * 32 + srow) * 64 + sseg * 8]);
      const u16* gb = B + bBase + (size_t)(bi * 32 + srow) * K + kt + ssw;
      gload_lds16(gb, &Bsm[(bi * 32 + srow) * 64 + sseg * 8]);
    }
    __syncthreads();
#pragma unroll
    for (int ks = 0; ks < 2; ++ks) {
      bf16x8 av[4], bv[4];
#pragma unroll
      for (int m = 0; m < 4; ++m)
        av[m] = *(const bf16x8*)&Asm[(wr * 64 + m * 16 + l15) * 64 +
                                     (((ks * 4 + seg0) ^ lx7) * 8)];
#pragma unroll
      for (int n = 0; n < 4; ++n)
        bv[n] = *(const bf16x8*)&Bsm[(wc * 64 + n * 16 + l15) * 64 +
                                     (((ks * 4 + seg0) ^ lx7) * 8)];
#pragma unroll
      for (int m = 0; m < 4; ++m)
#pragma unroll
        for (int n = 0; n < 4; ++n)
          acc[m][n] = __builtin_amdgcn_mfma_f32_16x16x32_bf16(av[m], bv[n], acc[m][n], 0, 0, 0);
    }
  }

  if (EPI == 4) {
    // ---- fused kern epilogue: kpart[bnIdx*2+wc][i][t] = sum_j leaky(H[i][j])*W2[t][j] ----
    const int g = lane >> 4;
    float* kp = (float*)Cout + (size_t)((bn >> 7) * 2 + wc) * 36864;   // 4096*9
#pragma unroll
    for (int m = 0; m < 4; ++m) {
#pragma unroll
      for (int jr = 0; jr < 4; ++jr) {
        const int i = bm + wr * 64 + m * 16 + g * 4 + jr;
        float s[9];
#pragma unroll
        for (int t = 0; t < 9; ++t) s[t] = 0.f;
#pragma unroll
        for (int n = 0; n < 4; ++n) {
          float v = acc[m][n][jr];
          v = v >= 0.f ? v : 0.1f * v;
          const int col = bn + wc * 64 + n * 16 + l15;
#pragma unroll
          for (int t = 0; t < 9; ++t) s[t] += v * bias[t * 4096 + col];   // bias := W2
        }
#pragma unroll
        for (int off = 1; off < 16; off <<= 1) {
#pragma unroll
          for (int t = 0; t < 9; ++t) s[t] += __shfl_xor(s[t], off);
        }
        if (l15 == 0) {
#pragma unroll
          for (int t = 0; t < 9; ++t) kp[(size_t)i * 9 + t] = s[t];
        }
      }
    }
  } else {
    // epilogue: C/D layout col=lane&15, row=(lane>>4)*4+reg  [m89-verified]
#pragma unroll
    for (int m = 0; m < 4; ++m) {
      const int row0 = bm + wr * 64 + m * 16 + (lane >> 4) * 4;
#pragma unroll
      for (int n = 0; n < 4; ++n) {
        const int col = bn + wc * 64 + n * 16 + l15;
#pragma unroll
        for (int j = 0; j < 4; ++j) {
          const int row = row0 + j;
          float v = acc[m][n][j];
          const size_t idx = (size_t)row * N + col;
          if (EPI == 1) {
            v = 1.f / (1.f + __expf(-v));
            ((u16*)Cout)[idx] = f2bf(v);
          } else if (EPI == 3) {
            ((float*)Cout)[(size_t)blockIdx.z * ((size_t)M * N) + idx] = v;
          } else {  // EPI == 5
            v += bias[row] + bf2f(degb[idx]) * bf2f(att[idx]);
            ((float*)Cout)[idx] = v;
          }
        }
      }
    }
  }
}

extern "C" void kernel_launch(void* const* d_in, const int* in_sizes, int n_in,
                              void* d_out, int out_size, void* d_ws, size_t ws_size,
                              hipStream_t stream) {
  const float* xc  = (const float*)d_in[0];   // (1,4096,64,64)
  const float* deg = (const float*)d_in[1];   // (4096,4096)
  const float* W1  = (const float*)d_in[2];   // (4096,4096)
  const float* W2  = (const float*)d_in[3];   // (9,4096)
  const float* Wc  = (const float*)d_in[4];   // (4096,4096)
  const float* bc  = (const float*)d_in[5];   // (4096,)
  const float* Wd1 = (const float*)d_in[6];   // (512,4096)
  const float* Wd2 = (const float*)d_in[7];   // (4096,512)
  float* out = (float*)d_out;

  char* ws = (char*)d_ws;
  const size_t MB = 1ull << 20;
  u16* RA    = (u16*)(ws + 0 * MB);     // 32MB: degT -> W1_b -> V -> Wc_b
  u16* RB    = (u16*)(ws + 32 * MB);    // 32MB: deg_b (live entire run)
  u16* RC    = (u16*)(ws + 64 * MB);    // 32MB: hid partials(f32) -> kpart(f32) -> Vt
  u16* RATT  = (u16*)(ws + 96 * MB);    // 32MB: att (bf16)
  u16* WD1B  = (u16*)(ws + 128 * MB);   // 4MB
  u16* WD2B  = (u16*)(ws + 132 * MB);   // 4MB
  u16* HIDT  = (u16*)(ws + 136 * MB);   // 4MB
  float* KERN = (float*)(ws + 140 * MB); // 144KB

  // ---- CA branch ----
  cast_bf16_kernel<<<2048, 256, 0, stream>>>(Wd1, WD1B, 512 * 4096 / 4);
  cast_bf16_kernel<<<2048, 256, 0, stream>>>(Wd2, WD2B, 4096 * 512 / 4);
  deg_prep_kernel<<<dim3(64, 64), 256, 0, stream>>>(deg, RB, RA);   // deg_b(RB), degT(RA)
  // hidT[p][o] = sum_c degT[p][c]*Wd1[o][c] : M=4096 N=512 K=4096, split-K=4 -> f32 partials
  gemm_nt<3><<<dim3(4, 32, 4), 256, 0, stream>>>(RA, WD1B, (float*)RC, 4096, 512, 4096,
                                                 nullptr, nullptr, nullptr);
  combine_leaky_kernel<<<2048, 256, 0, stream>>>((const float*)RC, HIDT, 4096 * 512 / 4);
  // att[o][p] = sigmoid(sum_k Wd2[o][k]*hidT[p][k]) : M=4096 N=4096 K=512
  gemm_nt<1><<<dim3(32, 32), 256, 0, stream>>>(WD2B, HIDT, RATT, 4096, 4096, 512,
                                               nullptr, nullptr, nullptr);

  // ---- dynamic kernel generation (H never materialized) ----
  cast_bf16_kernel<<<16384, 256, 0, stream>>>(W1, RA, 4096 * 4096 / 4);   // W1_b (degT dead)
  // kpart[slice][i][t] = sum_j leaky(deg_i . W1_j) * W2[t][j]  (kpart -> RC, hid partials dead)
  gemm_nt<4><<<dim3(32, 32), 256, 0, stream>>>(RB, RA, (float*)RC, 4096, 4096, 4096,
                                               W2, nullptr, nullptr);
  kpart_reduce_kernel<<<144, 256, 0, stream>>>((const float*)RC, KERN);

  // ---- depthwise conv + transpose ----
  dwconv_kernel<<<4096, 256, 0, stream>>>(xc, KERN, RA);                  // V -> RA (W1_b dead)
  transpose_bf16_kernel<<<dim3(64, 64), 256, 0, stream>>>(RA, RC);        // Vt -> RC (kpart dead)

  // ---- 1x1 conv + fused epilogue ----
  cast_bf16_kernel<<<16384, 256, 0, stream>>>(Wc, RA, 4096 * 4096 / 4);   // Wc_b -> RA (V dead)
  // out[o][p] = sum_c Wc[o][c]*Vt[p][c] + bc[o] + deg_b[o][p]*att[o][p] : 4096^3
  gemm_nt<5><<<dim3(32, 32), 256, 0, stream>>>(RA, RC, out, 4096, 4096, 4096,
                                               bc, RATT, RB);
}